// Round 6
// baseline (192.982 us; speedup 1.0000x reference)
//
#include <hip/hip_runtime.h>
#include <hip/hip_bf16.h>
#include <stdint.h>

#define BB 2
#define CC 256
#define HH 96
#define WW 320
#define NPIX 16384
#define NLAY 5
#define KDIM 1280   // CC*NLAY
#define NDIM 32768  // BB*NPIX
#define NKT (KDIM / 32)   // 40 K-tiles
#define NGRP 256    // NDIM/128 output row groups (k46 blocks)
#define BSP 264     // Bs row pitch in bf16 (256 + 8 pad: frag-read bank spread)

typedef float f32x4 __attribute__((ext_vector_type(4)));
typedef float f32x2 __attribute__((ext_vector_type(2)));
typedef __bf16 bf16x8 __attribute__((ext_vector_type(8)));
typedef __bf16 bf16x4 __attribute__((ext_vector_type(4)));

// ---------- K1 (+K3+K5 fused as extra blocks): ----------
// blocks [0,480): box geometry + Wc repack (overlaps with k1, R4).
//   K3 also emits mask8[g*5+n] = OR(vis) over each 128-pix group (R5):
//   one byte per (group,layer), single writer, no atomics/init.
// blocks [480, 480+1536): cumsum along W + transpose (B,C,H,W)->(B,H,W,C),
//   32-ch blocks / full 128B-line ownership (R3), LDS-staged reads (R4).
__global__ __launch_bounds__(1024) void k1f(const float* __restrict__ feat,
                                            float* __restrict__ integ,
                                            const float* __restrict__ gridp,
                                            const float* __restrict__ calib,
                                            const float* __restrict__ Wc,
                                            float4* __restrict__ coords,
                                            float* __restrict__ scales,
                                            __bf16* __restrict__ Wbf,
                                            uint8_t* __restrict__ mask8) {
  const int bid = blockIdx.x;
  if (bid < 480) {
    // ---- K3/K5 part ----
    const int vbid = bid * 4 + (threadIdx.x >> 8);
    const int vt = threadIdx.x & 255;
    if (vbid >= 640) {                  // K5: repack Wc (co, c*5+n) -> bf16 (co, n*256+c)
      int o = (vbid - 640) * 256 + vt;
      int co = o / KDIM;
      int kk = o % KDIM;
      int n = kk >> 8;
      int c = kk & 255;
      Wbf[o] = (__bf16)Wc[co * KDIM + c * NLAY + n];
      return;
    }
    // K3: one thread per box.
    int box = vbid * 256 + vt;          // ((b*5+n)<<14) | pix
    int pix = box & (NPIX - 1);
    int bn = box >> 14;
    int n = bn % NLAY;
    int b = bn / NLAY;
    const float* cb = calib + b * 12;
    float c00 = cb[0], c01 = cb[1], c02 = cb[2], c03 = cb[3];
    float c10 = cb[4], c11 = cb[5], c12 = cb[6], c13 = cb[7];
    float c20 = cb[8], c21 = cb[9], c22 = cb[10], c23 = cb[11];
    float gx = gridp[pix * 3 + 0], gy = gridp[pix * 3 + 1], gz = gridp[pix * 3 + 2];
    float zoff = 32.0f * (float)n;
    const float ox[8] = {-12.5f, 12.5f, 12.5f, -12.5f, -12.5f, 12.5f, 12.5f, -12.5f};
    const float oy[8] = {-12.5f, -12.5f, 12.5f, 12.5f, -12.5f, -12.5f, 12.5f, 12.5f};
    float xmn = 1e30f, ymn = 1e30f, xmx = -1e30f, ymx = -1e30f;
#pragma unroll
    for (int k = 0; k < 8; ++k) {
      float X = gx + ox[k];
      float Y = gy + oy[k];
      float Z = gz + zoff + ((k >= 4) ? 32.0f : 0.0f);
      float px = c00 * X + c01 * Y + c02 * Z + c03;
      float py = c10 * X + c11 * Y + c12 * Z + c13;
      float pz = c20 * X + c21 * Y + c22 * Z + c23;
      float d = fmaxf(pz, 1e-6f);
      float nx = fminf(fmaxf(2.0f * (px / d) / 320.0f - 1.0f, -1.0f), 0.95f);
      float ny = fminf(fmaxf(2.0f * (py / d) / 96.0f - 1.0f, -1.0f), 0.95f);
      xmn = fminf(xmn, nx); xmx = fmaxf(xmx, nx);
      ymn = fminf(ymn, ny); ymx = fmaxf(ymx, ny);
    }
    float dx = xmx - xmn, dy = ymx - ymn;
    float area = (dx * dy) * 30720.0f + 1e-6f;
    bool vis = (area > 1e-6f) && (area < 9216.0f);
    {
      __shared__ uint32_t kf[16];
      unsigned long long bal = __ballot(vis);
      if ((threadIdx.x & 63) == 0) kf[threadIdx.x >> 6] = (bal != 0ull) ? 1u : 0u;
      __syncthreads();
      if (vt == 0) {
        int vb = threadIdx.x >> 8;      // vbid-local 0..3
        int vbid2 = bid * 4 + vb;
        int bn2 = vbid2 >> 6;
        int n2 = bn2 % NLAY, b2 = bn2 / NLAY;
        int g0 = b2 * 128 + (vbid2 & 63) * 2;
        mask8[g0 * 5 + n2]       = (uint8_t)(kf[vb * 4 + 0] | kf[vb * 4 + 1]);
        mask8[(g0 + 1) * 5 + n2] = (uint8_t)(kf[vb * 4 + 2] | kf[vb * 4 + 3]);
      }
    }
    float X0 = ((xmn + 1.0f) * 320.0f - 1.0f) * 0.5f;
    float Y0 = ((ymn + 1.0f) * 96.0f - 1.0f) * 0.5f;
    float X1 = ((xmx + 1.0f) * 320.0f - 1.0f) * 0.5f;
    float Y1 = ((ymx + 1.0f) * 96.0f - 1.0f) * 0.5f;
    coords[box] = make_float4(X0, Y0, X1, Y1);
    scales[box] = vis ? 1.0f / area : 0.0f;
    return;
  }
  // ---- K1 part: 32 channels per block, wave scans 2 channel rows ----
  __shared__ float tile[WW * 33];       // 42.2 KB; 1024 thr -> 2 blocks/CU
  const int t = threadIdx.x;
  const int wave = t >> 6;
  const int lane = t & 63;
  const int kb = bid - 480;
  const int cg = kb & 7;
  const int h = (kb >> 3) % HH;
  const int b = kb / (8 * HH);
  const int c0 = cg * 32;

  // phase L: coalesced float4 global reads -> ds_write_b128, layout [cr][w]
  {
    const float* fb = feat + (size_t)((b * CC + c0) * HH + h) * WW;
    const size_t crstride = (size_t)HH * WW;
#pragma unroll
    for (int r = 0; r < 3; ++r) {
      int idx = r * 1024 + t;           // 0..2559 float4 slots
      if (idx < 2560) {
        int cr = idx / 80;              // channel row 0..31
        int wq = idx - cr * 80;         // float4 slot 0..79
        f32x4 v = *(const f32x4*)(fb + cr * crstride + wq * 4);
        *(f32x4*)(&tile[cr * WW + wq * 4]) = v;
      }
    }
  }
  __syncthreads();
  // phase R: lane reads its two 5-float runs (channels ca=2*wave, cb=+1)
  const int ca = wave * 2, cbn = wave * 2 + 1;
  float va[5], vb[5];
#pragma unroll
  for (int j = 0; j < 5; ++j) va[j] = tile[ca * WW + lane * 5 + j];
#pragma unroll
  for (int j = 0; j < 5; ++j) vb[j] = tile[cbn * WW + lane * 5 + j];
#pragma unroll
  for (int j = 1; j < 5; ++j) { va[j] += va[j - 1]; vb[j] += vb[j - 1]; }
  float ta = va[4], tb = vb[4];
  float ia = ta, ib = tb;
#pragma unroll
  for (int d = 1; d < 64; d <<= 1) {
    float ua = __shfl_up(ia, d, 64);
    float ub = __shfl_up(ib, d, 64);
    if (lane >= d) { ia += ua; ib += ub; }
  }
  float pa = ia - ta, pb = ib - tb;     // exclusive prefixes
#pragma unroll
  for (int j = 0; j < 5; ++j) { va[j] += pa; vb[j] += pb; }
  __syncthreads();                      // all runs read before tile is reused
  // phase T: write scanned values transposed [w][c'], pitch 33
#pragma unroll
  for (int j = 0; j < 5; ++j) {
    int w = lane * 5 + j;
    tile[w * 33 + ca]  = va[j];
    tile[w * 33 + cbn] = vb[j];
  }
  __syncthreads();
  // phase S: float4 stores; per wave-instr 8 w-rows x 128B full-line segments
  float* dst = integ + (size_t)((b * HH + h) * WW) * CC + cg * 32;
#pragma unroll
  for (int r = 0; r < 3; ++r) {
    int idx = r * 1024 + t;             // 0..2559
    if (idx < 2560) {
      int w = idx >> 3;
      int cq = (idx & 7) * 4;
      float4 o = make_float4(tile[w * 33 + cq + 0], tile[w * 33 + cq + 1],
                             tile[w * 33 + cq + 2], tile[w * 33 + cq + 3]);
      *(float4*)(dst + (size_t)w * CC + cq) = o;
    }
  }
}

// ---------- K2: cumsum along H, in place on (B,H,W,C) ----------
// Two-level scan, f32x4 per lane (1KB segments/wave-instr, 24-deep ILP).
__global__ __launch_bounds__(256) void k2_scan(float* __restrict__ integ) {
  const int blk = blockIdx.x;            // (b, w)
  const int w = blk % WW;
  const int b = blk / WW;
  const int g = threadIdx.x >> 6;        // 0..3 h-group
  const int l = threadIdx.x & 63;
  float* base = integ + ((size_t)(b * HH + g * 24) * WW + w) * CC + l * 4;
  const size_t stride = (size_t)WW * CC;
  f32x4 v[24];
#pragma unroll
  for (int i = 0; i < 24; ++i) v[i] = *(const f32x4*)(base + (size_t)i * stride);
#pragma unroll
  for (int i = 1; i < 24; ++i) v[i] += v[i - 1];
  __shared__ f32x4 part[4][64];
  part[g][l] = v[23];
  __syncthreads();
  f32x4 off = {0.f, 0.f, 0.f, 0.f};
#pragma unroll
  for (int gg = 0; gg < 3; ++gg)
    if (gg < g) off += part[gg][l];
#pragma unroll
  for (int i = 0; i < 24; ++i) *(f32x4*)(base + (size_t)i * stride) = v[i] + off;
}

// ---------- async 16B global -> LDS ----------
__device__ __forceinline__ void glds16(const void* g, void* l) {
  __builtin_amdgcn_global_load_lds(
      (const __attribute__((address_space(1))) void*)g,
      (__attribute__((address_space(3))) void*)(uint32_t)(uintptr_t)l,
      16, 0, 0);
}

// ---------- K46: fused vox-gather + GEMM ----------
// R6: k4's vox tile and k6's B tile are congruent (128-pixel group x layer),
// so compute vox straight into LDS and never round-trip d*168MB through HBM.
// One block per group (grid 256 = 1/CU, 512 thr = 8 waves), output tile
// 128 pix x 256 co (waves 4M x 2N, acc 4x4 frags each).
// Per visible layer: PHASE G — each wave gathers 16 box rows (k4 tap math,
// lane owns 4 ch; one full 256-ch row per wave-instr) -> Bs[128][BSP] bf16
// (pad 264: frag reads at pitch 132 words, 132%32=4 -> 2-way, ~free).
// PHASE M — 8 K-tiles vs Wbf via glds16 ring-3/depth-2 (16KB/tile, 2 glds
// per thread per stage): vmcnt(2) steady / vmcnt(0) last + raw s_barrier.
// Single-barrier safety: stage at kk targets buf (kk+2)%3 = the buffer whose
// readers (iter kk-1) consumed their frags before barrier kk. Gather-phase
// VMEM never overlaps the counted vmcnt window (the G->M __syncthreads
// drains everything). Fully-invisible groups: acc=0 -> out = relu(bias).
__global__ __launch_bounds__(512) void k46(const __bf16* __restrict__ A,   // Wbf 256 x 1280
                                           const float* __restrict__ integ,
                                           const float4* __restrict__ coords,
                                           const float* __restrict__ scales,
                                           const float* __restrict__ bias,
                                           float* __restrict__ out,
                                           const uint8_t* __restrict__ mask8) {
  __shared__ __align__(16) __bf16 As[3][256 * 32];   // 48 KB
  __shared__ __align__(16) __bf16 Bs[128 * BSP];     // 66 KB
  const int g = blockIdx.x;
  const int b = g >> 7;
  const int pix0 = (g & 127) * 128;
  const int tid = threadIdx.x;
  const int lane = tid & 63;
  const int wave = tid >> 6;
  const int wm = (wave >> 1) * 64;     // 4 M-positions
  const int wn = (wave & 1) * 64;      // 2 N-positions
  const int r16 = lane & 15;
  const int q4 = lane >> 4;

  // active-layer list (block-uniform)
  int ln[NLAY], nact = 0;
#pragma unroll
  for (int n = 0; n < NLAY; ++n)
    if (mask8[g * 5 + n]) ln[nact++] = n;

  f32x4 acc[4][4];
#pragma unroll
  for (int i = 0; i < 4; ++i)
#pragma unroll
    for (int j = 0; j < 4; ++j)
      acc[i][j] = f32x4{0.f, 0.f, 0.f, 0.f};

  auto stage = [&](int buf, int kt) {  // Wbf K-tile: 256 rows x 32 ch = 16 KB
    const int k0 = kt * 32;
#pragma unroll
    for (int rr = 0; rr < 2; ++rr) {
      const int base_row = rr * 128 + wave * 16;
      const int row = base_row + (lane >> 2);
      const int gch = (lane & 3) ^ ((row >> 1) & 3);
      glds16(A + (size_t)row * KDIM + k0 + gch * 8,
             (void*)(&As[buf][base_row * 32] + lane * 8));
    }
  };

  for (int la = 0; la < nact; ++la) {
    const int n = ln[la];
    const int bn = b * NLAY + n;
    // ---- PHASE G: gather 16 vox rows per wave into Bs ----
    const float* gbase = integ + (size_t)(b * HH) * WW * CC + lane * 4;
#pragma unroll 4
    for (int u = 0; u < 16; ++u) {
      const int row = wave * 16 + u;
      const int box = (bn << 14) | (pix0 + row);
      bf16x4* dst = (bf16x4*)(&Bs[row * BSP + lane * 4]);
      const float scale = scales[box];
      if (scale == 0.f) {               // wave-uniform
        *dst = bf16x4{(__bf16)0.f, (__bf16)0.f, (__bf16)0.f, (__bf16)0.f};
        continue;
      }
      const float4 q = coords[box];
      float xw[4]; int xi[4];
      float yw[4]; int yi[4];
      {
        float f0 = floorf(q.x); int i0 = (int)f0; float w1 = q.x - f0;
        xw[0] = (i0 >= 0 && i0 < WW) ? (1.f - w1) : 0.f;
        xw[1] = (i0 + 1 < WW) ? w1 : 0.f;
        xi[0] = min(max(i0, 0), WW - 1); xi[1] = min(max(i0 + 1, 0), WW - 1);
        float f1 = floorf(q.z); int i1 = (int)f1; float v1 = q.z - f1;
        xw[2] = (i1 >= 0 && i1 < WW) ? -(1.f - v1) : 0.f;
        xw[3] = (i1 + 1 < WW) ? -v1 : 0.f;
        xi[2] = min(max(i1, 0), WW - 1); xi[3] = min(max(i1 + 1, 0), WW - 1);
      }
      {
        float f0 = floorf(q.y); int j0 = (int)f0; float w1 = q.y - f0;
        yw[0] = (j0 >= 0 && j0 < HH) ? (1.f - w1) : 0.f;
        yw[1] = (j0 + 1 < HH) ? w1 : 0.f;
        yi[0] = min(max(j0, 0), HH - 1); yi[1] = min(max(j0 + 1, 0), HH - 1);
        float f1 = floorf(q.w); int j1 = (int)f1; float v1 = q.w - f1;
        yw[2] = (j1 >= 0 && j1 < HH) ? -(1.f - v1) : 0.f;
        yw[3] = (j1 + 1 < HH) ? -v1 : 0.f;
        yi[2] = min(max(j1, 0), HH - 1); yi[3] = min(max(j1 + 1, 0), HH - 1);
      }
      f32x4 val = {0.f, 0.f, 0.f, 0.f};
#pragma unroll
      for (int jj = 0; jj < 4; ++jj) {
        if (yw[jj] == 0.f) continue;        // wave-uniform
        const float* rp = gbase + (size_t)yi[jj] * WW * CC;
        f32x4 rs = {0.f, 0.f, 0.f, 0.f};
#pragma unroll
        for (int ii = 0; ii < 4; ++ii) {
          if (xw[ii] != 0.f) {
            f32x4 v = *(const f32x4*)(rp + (size_t)xi[ii] * CC);
            rs += xw[ii] * v;
          }
        }
        val += yw[jj] * rs;
      }
      val *= scale;
      *dst = bf16x4{(__bf16)val.x, (__bf16)val.y, (__bf16)val.z, (__bf16)val.w};
    }
    __syncthreads();                    // Bs ready; drains ALL vmem (gathers)
    // ---- PHASE M: 8 K-tiles of this layer ----
    const int base = n * 8;
    stage(0, base);
    stage(1, base + 1);
    for (int kk = 0; kk < 8; ++kk) {
      const int cur = kk % 3;
      if (kk < 7) __builtin_amdgcn_s_waitcnt(0xF72);  // vmcnt(2): oldest stage done
      else        __builtin_amdgcn_s_waitcnt(0xF70);  // vmcnt(0)
      __builtin_amdgcn_s_barrier();
      if (kk + 2 < 8) stage((kk + 2) % 3, base + kk + 2);
      bf16x8 af[4], bg[4];
#pragma unroll
      for (int i = 0; i < 4; ++i) {
        int m = wm + i * 16 + r16;
        af[i] = *(const bf16x8*)(&As[cur][m * 32] + (q4 ^ ((m >> 1) & 3)) * 8);
      }
#pragma unroll
      for (int j = 0; j < 4; ++j) {
        int nr = wn + j * 16 + r16;
        bg[j] = *(const bf16x8*)(&Bs[nr * BSP + kk * 32 + q4 * 8]);
      }
#pragma unroll
      for (int i = 0; i < 4; ++i)
#pragma unroll
        for (int j = 0; j < 4; ++j)
          acc[i][j] = __builtin_amdgcn_mfma_f32_16x16x32_bf16(af[i], bg[j], acc[i][j], 0, 0, 0);
    }
    __syncthreads();                    // all Bs reads done before next gather
  }

  // ---- epilogue: out[(b*CC+co)*NPIX + pix] = relu(acc + bias) ----
#pragma unroll
  for (int i = 0; i < 4; ++i) {
#pragma unroll
    for (int j = 0; j < 4; ++j) {
      int pix = pix0 + wn + j * 16 + r16;
#pragma unroll
      for (int r = 0; r < 4; ++r) {
        int co = wm + i * 16 + q4 * 4 + r;
        float v = acc[i][j][r] + bias[co];
        out[(size_t)(b * CC + co) * NPIX + pix] = fmaxf(v, 0.f);
      }
    }
  }
}

extern "C" void kernel_launch(void* const* d_in, const int* in_sizes, int n_in,
                              void* d_out, int out_size, void* d_ws, size_t ws_size,
                              hipStream_t stream) {
  const float* feat  = (const float*)d_in[0];
  const float* calib = (const float*)d_in[1];
  const float* grid  = (const float*)d_in[2];
  const float* Wc    = (const float*)d_in[3];
  const float* bc    = (const float*)d_in[4];
  float* out = (float*)d_out;

  char* ws = (char*)d_ws;
  const size_t SZ_INTEG = (size_t)BB * HH * WW * CC * 4;   // 62,914,560
  const size_t SZ_VOX   = (size_t)NDIM * KDIM * 2;         // 83,886,080 (unused slot kept)
  const size_t SZ_WBF   = (size_t)CC * KDIM * 2;           //    655,360
  const size_t SZ_CRD   = (size_t)BB * NLAY * NPIX * 16;   //  2,621,440
  const size_t SZ_SCL   = (size_t)BB * NLAY * NPIX * 4;    //    655,360
  const size_t SZ_MSK   = (size_t)NGRP * NLAY;             //      1,280
  if (ws_size < SZ_INTEG + SZ_VOX + SZ_WBF + SZ_CRD + SZ_SCL + SZ_MSK) return;

  float*   integ  = (float*)ws;
  __bf16*  Wbf    = (__bf16*)(ws + SZ_INTEG + SZ_VOX);
  float4*  coords = (float4*)(ws + SZ_INTEG + SZ_VOX + SZ_WBF);
  float*   scales = (float*)(ws + SZ_INTEG + SZ_VOX + SZ_WBF + SZ_CRD);
  uint8_t* mask8  = (uint8_t*)(ws + SZ_INTEG + SZ_VOX + SZ_WBF + SZ_CRD + SZ_SCL);

  k1f<<<dim3(BB * HH * 8 + 480), dim3(1024), 0, stream>>>(
      feat, integ, grid, calib, Wc, coords, scales, Wbf, mask8);
  k2_scan<<<dim3(BB * WW), dim3(256), 0, stream>>>(integ);
  k46<<<dim3(NGRP), dim3(512), 0, stream>>>(Wbf, integ, coords, scales, bc, out, mask8);
}

// Round 7
// 170.083 us; speedup vs baseline: 1.1346x; 1.1346x over previous
//
#include <hip/hip_runtime.h>
#include <hip/hip_bf16.h>
#include <stdint.h>

#define BB 2
#define CC 256
#define HH 96
#define WW 320
#define NPIX 16384
#define NLAY 5
#define KDIM 1280   // CC*NLAY
#define NDIM 32768  // BB*NPIX
#define NGRP 256    // NDIM/128 mask groups
#define BSP 264     // Bs row pitch in bf16 (256 + 8 pad)

typedef float f32x4 __attribute__((ext_vector_type(4)));
typedef float f32x2 __attribute__((ext_vector_type(2)));
typedef __bf16 bf16x8 __attribute__((ext_vector_type(8)));
typedef __bf16 bf16x4 __attribute__((ext_vector_type(4)));

// ---------- K1 (+K3+K5 fused as extra blocks): ----------
// blocks [0,480): box geometry + Wc repack (overlaps with k1, R4).
//   K3 also emits mask8[g*5+n] = OR(vis) over each 128-pix group (R5).
// blocks [480, 480+1536): cumsum along W + transpose (B,C,H,W)->(B,H,W,C),
//   32-ch blocks / full 128B-line ownership (R3), LDS-staged reads (R4).
__global__ __launch_bounds__(1024) void k1f(const float* __restrict__ feat,
                                            float* __restrict__ integ,
                                            const float* __restrict__ gridp,
                                            const float* __restrict__ calib,
                                            const float* __restrict__ Wc,
                                            float4* __restrict__ coords,
                                            float* __restrict__ scales,
                                            __bf16* __restrict__ Wbf,
                                            uint8_t* __restrict__ mask8) {
  const int bid = blockIdx.x;
  if (bid < 480) {
    // ---- K3/K5 part ----
    const int vbid = bid * 4 + (threadIdx.x >> 8);
    const int vt = threadIdx.x & 255;
    if (vbid >= 640) {                  // K5: repack Wc (co, c*5+n) -> bf16 (co, n*256+c)
      int o = (vbid - 640) * 256 + vt;
      int co = o / KDIM;
      int kk = o % KDIM;
      int n = kk >> 8;
      int c = kk & 255;
      Wbf[o] = (__bf16)Wc[co * KDIM + c * NLAY + n];
      return;
    }
    // K3: one thread per box.
    int box = vbid * 256 + vt;          // ((b*5+n)<<14) | pix
    int pix = box & (NPIX - 1);
    int bn = box >> 14;
    int n = bn % NLAY;
    int b = bn / NLAY;
    const float* cb = calib + b * 12;
    float c00 = cb[0], c01 = cb[1], c02 = cb[2], c03 = cb[3];
    float c10 = cb[4], c11 = cb[5], c12 = cb[6], c13 = cb[7];
    float c20 = cb[8], c21 = cb[9], c22 = cb[10], c23 = cb[11];
    float gx = gridp[pix * 3 + 0], gy = gridp[pix * 3 + 1], gz = gridp[pix * 3 + 2];
    float zoff = 32.0f * (float)n;
    const float ox[8] = {-12.5f, 12.5f, 12.5f, -12.5f, -12.5f, 12.5f, 12.5f, -12.5f};
    const float oy[8] = {-12.5f, -12.5f, 12.5f, 12.5f, -12.5f, -12.5f, 12.5f, 12.5f};
    float xmn = 1e30f, ymn = 1e30f, xmx = -1e30f, ymx = -1e30f;
#pragma unroll
    for (int k = 0; k < 8; ++k) {
      float X = gx + ox[k];
      float Y = gy + oy[k];
      float Z = gz + zoff + ((k >= 4) ? 32.0f : 0.0f);
      float px = c00 * X + c01 * Y + c02 * Z + c03;
      float py = c10 * X + c11 * Y + c12 * Z + c13;
      float pz = c20 * X + c21 * Y + c22 * Z + c23;
      float d = fmaxf(pz, 1e-6f);
      float nx = fminf(fmaxf(2.0f * (px / d) / 320.0f - 1.0f, -1.0f), 0.95f);
      float ny = fminf(fmaxf(2.0f * (py / d) / 96.0f - 1.0f, -1.0f), 0.95f);
      xmn = fminf(xmn, nx); xmx = fmaxf(xmx, nx);
      ymn = fminf(ymn, ny); ymx = fmaxf(ymx, ny);
    }
    float dx = xmx - xmn, dy = ymx - ymn;
    float area = (dx * dy) * 30720.0f + 1e-6f;
    bool vis = (area > 1e-6f) && (area < 9216.0f);
    {
      __shared__ uint32_t kf[16];
      unsigned long long bal = __ballot(vis);
      if ((threadIdx.x & 63) == 0) kf[threadIdx.x >> 6] = (bal != 0ull) ? 1u : 0u;
      __syncthreads();
      if (vt == 0) {
        int vb = threadIdx.x >> 8;      // vbid-local 0..3
        int vbid2 = bid * 4 + vb;
        int bn2 = vbid2 >> 6;
        int n2 = bn2 % NLAY, b2 = bn2 / NLAY;
        int g0 = b2 * 128 + (vbid2 & 63) * 2;
        mask8[g0 * 5 + n2]       = (uint8_t)(kf[vb * 4 + 0] | kf[vb * 4 + 1]);
        mask8[(g0 + 1) * 5 + n2] = (uint8_t)(kf[vb * 4 + 2] | kf[vb * 4 + 3]);
      }
    }
    float X0 = ((xmn + 1.0f) * 320.0f - 1.0f) * 0.5f;
    float Y0 = ((ymn + 1.0f) * 96.0f - 1.0f) * 0.5f;
    float X1 = ((xmx + 1.0f) * 320.0f - 1.0f) * 0.5f;
    float Y1 = ((ymx + 1.0f) * 96.0f - 1.0f) * 0.5f;
    coords[box] = make_float4(X0, Y0, X1, Y1);
    scales[box] = vis ? 1.0f / area : 0.0f;
    return;
  }
  // ---- K1 part: 32 channels per block, wave scans 2 channel rows ----
  __shared__ float tile[WW * 33];       // 42.2 KB; 1024 thr -> 2 blocks/CU
  const int t = threadIdx.x;
  const int wave = t >> 6;
  const int lane = t & 63;
  const int kb = bid - 480;
  const int cg = kb & 7;
  const int h = (kb >> 3) % HH;
  const int b = kb / (8 * HH);
  const int c0 = cg * 32;

  // phase L: coalesced float4 global reads -> ds_write_b128, layout [cr][w]
  {
    const float* fb = feat + (size_t)((b * CC + c0) * HH + h) * WW;
    const size_t crstride = (size_t)HH * WW;
#pragma unroll
    for (int r = 0; r < 3; ++r) {
      int idx = r * 1024 + t;           // 0..2559 float4 slots
      if (idx < 2560) {
        int cr = idx / 80;              // channel row 0..31
        int wq = idx - cr * 80;         // float4 slot 0..79
        f32x4 v = *(const f32x4*)(fb + cr * crstride + wq * 4);
        *(f32x4*)(&tile[cr * WW + wq * 4]) = v;
      }
    }
  }
  __syncthreads();
  // phase R: lane reads its two 5-float runs (channels ca=2*wave, cb=+1)
  const int ca = wave * 2, cbn = wave * 2 + 1;
  float va[5], vb[5];
#pragma unroll
  for (int j = 0; j < 5; ++j) va[j] = tile[ca * WW + lane * 5 + j];
#pragma unroll
  for (int j = 0; j < 5; ++j) vb[j] = tile[cbn * WW + lane * 5 + j];
#pragma unroll
  for (int j = 1; j < 5; ++j) { va[j] += va[j - 1]; vb[j] += vb[j - 1]; }
  float ta = va[4], tb = vb[4];
  float ia = ta, ib = tb;
#pragma unroll
  for (int d = 1; d < 64; d <<= 1) {
    float ua = __shfl_up(ia, d, 64);
    float ub = __shfl_up(ib, d, 64);
    if (lane >= d) { ia += ua; ib += ub; }
  }
  float pa = ia - ta, pb = ib - tb;     // exclusive prefixes
#pragma unroll
  for (int j = 0; j < 5; ++j) { va[j] += pa; vb[j] += pb; }
  __syncthreads();                      // all runs read before tile is reused
  // phase T: write scanned values transposed [w][c'], pitch 33
#pragma unroll
  for (int j = 0; j < 5; ++j) {
    int w = lane * 5 + j;
    tile[w * 33 + ca]  = va[j];
    tile[w * 33 + cbn] = vb[j];
  }
  __syncthreads();
  // phase S: float4 stores; per wave-instr 8 w-rows x 128B full-line segments
  float* dst = integ + (size_t)((b * HH + h) * WW) * CC + cg * 32;
#pragma unroll
  for (int r = 0; r < 3; ++r) {
    int idx = r * 1024 + t;             // 0..2559
    if (idx < 2560) {
      int w = idx >> 3;
      int cq = (idx & 7) * 4;
      float4 o = make_float4(tile[w * 33 + cq + 0], tile[w * 33 + cq + 1],
                             tile[w * 33 + cq + 2], tile[w * 33 + cq + 3]);
      *(float4*)(dst + (size_t)w * CC + cq) = o;
    }
  }
}

// ---------- K2: cumsum along H, in place on (B,H,W,C) ----------
// Two-level scan, f32x4 per lane (1KB segments/wave-instr, 24-deep ILP).
__global__ __launch_bounds__(256) void k2_scan(float* __restrict__ integ) {
  const int blk = blockIdx.x;            // (b, w)
  const int w = blk % WW;
  const int b = blk / WW;
  const int g = threadIdx.x >> 6;        // 0..3 h-group
  const int l = threadIdx.x & 63;
  float* base = integ + ((size_t)(b * HH + g * 24) * WW + w) * CC + l * 4;
  const size_t stride = (size_t)WW * CC;
  f32x4 v[24];
#pragma unroll
  for (int i = 0; i < 24; ++i) v[i] = *(const f32x4*)(base + (size_t)i * stride);
#pragma unroll
  for (int i = 1; i < 24; ++i) v[i] += v[i - 1];
  __shared__ f32x4 part[4][64];
  part[g][l] = v[23];
  __syncthreads();
  f32x4 off = {0.f, 0.f, 0.f, 0.f};
#pragma unroll
  for (int gg = 0; gg < 3; ++gg)
    if (gg < g) off += part[gg][l];
#pragma unroll
  for (int i = 0; i < 24; ++i) *(f32x4*)(base + (size_t)i * stride) = v[i] + off;
}

// ---------- K46 v2: fused vox-gather + GEMM, latency/tail fixed ----------
// R6 failed structurally (1 block/CU, slowest-single-block tail, 8 waves/CU,
// barrier-laced: MfmaUtil 1.3%, VALU 8%, occ 11%). R7:
//  * 32-pixel blocks, grid 1024 = 4 blocks/CU, 32 waves/CU; dense groups
//    split 4-way -> tail /4.
//  * NO As staging: A-frags read DIRECTLY from global Wbf (640 KB,
//    L2-resident; af[i] = A[(wm+i*16+r16)*KDIM + k0 + q4*8] — exactly the
//    bytes the R5/R6 stage+swizzled-read pair delivered). Deletes all
//    stage/vmcnt/barrier machinery -> ZERO barriers in the MFMA phase, and
//    LDS drops to Bs-only 17 KB (what allows 4 blocks/CU).
//  * Bs gather (k4 tap math) unchanged from R6 (passed); per wave 4 boxes.
// Per visible layer: G (gather 32 rows -> Bs) -> sync -> M (8 K-tiles,
// unrolled, direct-A MFMA) -> sync. Invisible groups: acc=0 -> relu(bias).
__global__ __launch_bounds__(512) void k46(const __bf16* __restrict__ A,   // Wbf 256 x 1280
                                           const float* __restrict__ integ,
                                           const float4* __restrict__ coords,
                                           const float* __restrict__ scales,
                                           const float* __restrict__ bias,
                                           float* __restrict__ out,
                                           const uint8_t* __restrict__ mask8) {
  __shared__ __align__(16) __bf16 Bs[32 * BSP];      // 16.9 KB
  const int g = blockIdx.x;            // (b, 32-pix tile)
  const int b = g >> 9;
  const int pix0 = (g & 511) * 32;
  const int gm = b * 128 + (pix0 >> 7);   // 128-pix mask group
  const int tid = threadIdx.x;
  const int lane = tid & 63;
  const int wave = tid >> 6;
  const int wm = (wave >> 1) * 64;     // M quadrant (co)
  const int wn = (wave & 1) * 16;      // N half (pix)
  const int r16 = lane & 15;
  const int q4 = lane >> 4;

  // active-layer list (block-uniform)
  int ln[NLAY], nact = 0;
#pragma unroll
  for (int n = 0; n < NLAY; ++n)
    if (mask8[gm * 5 + n]) ln[nact++] = n;

  f32x4 acc[4];
#pragma unroll
  for (int i = 0; i < 4; ++i) acc[i] = f32x4{0.f, 0.f, 0.f, 0.f};

  for (int la = 0; la < nact; ++la) {
    const int n = ln[la];
    const int bn = b * NLAY + n;
    // ---- PHASE G: 4 boxes per wave -> Bs[32][BSP] ----
    const float* gbase = integ + (size_t)(b * HH) * WW * CC + lane * 4;
#pragma unroll
    for (int u = 0; u < 4; ++u) {
      const int row = wave * 4 + u;
      const int box = (bn << 14) | (pix0 + row);
      bf16x4* dst = (bf16x4*)(&Bs[row * BSP + lane * 4]);
      const float scale = scales[box];
      if (scale == 0.f) {               // wave-uniform
        *dst = bf16x4{(__bf16)0.f, (__bf16)0.f, (__bf16)0.f, (__bf16)0.f};
        continue;
      }
      const float4 q = coords[box];
      float xw[4]; int xi[4];
      float yw[4]; int yi[4];
      {
        float f0 = floorf(q.x); int i0 = (int)f0; float w1 = q.x - f0;
        xw[0] = (i0 >= 0 && i0 < WW) ? (1.f - w1) : 0.f;
        xw[1] = (i0 + 1 < WW) ? w1 : 0.f;
        xi[0] = min(max(i0, 0), WW - 1); xi[1] = min(max(i0 + 1, 0), WW - 1);
        float f1 = floorf(q.z); int i1 = (int)f1; float v1 = q.z - f1;
        xw[2] = (i1 >= 0 && i1 < WW) ? -(1.f - v1) : 0.f;
        xw[3] = (i1 + 1 < WW) ? -v1 : 0.f;
        xi[2] = min(max(i1, 0), WW - 1); xi[3] = min(max(i1 + 1, 0), WW - 1);
      }
      {
        float f0 = floorf(q.y); int j0 = (int)f0; float w1 = q.y - f0;
        yw[0] = (j0 >= 0 && j0 < HH) ? (1.f - w1) : 0.f;
        yw[1] = (j0 + 1 < HH) ? w1 : 0.f;
        yi[0] = min(max(j0, 0), HH - 1); yi[1] = min(max(j0 + 1, 0), HH - 1);
        float f1 = floorf(q.w); int j1 = (int)f1; float v1 = q.w - f1;
        yw[2] = (j1 >= 0 && j1 < HH) ? -(1.f - v1) : 0.f;
        yw[3] = (j1 + 1 < HH) ? -v1 : 0.f;
        yi[2] = min(max(j1, 0), HH - 1); yi[3] = min(max(j1 + 1, 0), HH - 1);
      }
      f32x4 val = {0.f, 0.f, 0.f, 0.f};
#pragma unroll
      for (int jj = 0; jj < 4; ++jj) {
        if (yw[jj] == 0.f) continue;        // wave-uniform
        const float* rp = gbase + (size_t)yi[jj] * WW * CC;
        f32x4 rs = {0.f, 0.f, 0.f, 0.f};
#pragma unroll
        for (int ii = 0; ii < 4; ++ii) {
          if (xw[ii] != 0.f) {
            f32x4 v = *(const f32x4*)(rp + (size_t)xi[ii] * CC);
            rs += xw[ii] * v;
          }
        }
        val += yw[jj] * rs;
      }
      val *= scale;
      *dst = bf16x4{(__bf16)val.x, (__bf16)val.y, (__bf16)val.z, (__bf16)val.w};
    }
    __syncthreads();                    // Bs ready
    // ---- PHASE M: 8 K-tiles, direct-global A frags, no barriers ----
    const int kbase = n * 256;
#pragma unroll
    for (int kk = 0; kk < 8; ++kk) {
      const int k0 = kbase + kk * 32;
      bf16x8 af[4];
#pragma unroll
      for (int i = 0; i < 4; ++i)
        af[i] = *(const bf16x8*)(A + (size_t)(wm + i * 16 + r16) * KDIM + k0 + q4 * 8);
      bf16x8 bg = *(const bf16x8*)(&Bs[(wn + r16) * BSP + kk * 32 + q4 * 8]);
#pragma unroll
      for (int i = 0; i < 4; ++i)
        acc[i] = __builtin_amdgcn_mfma_f32_16x16x32_bf16(af[i], bg, acc[i], 0, 0, 0);
    }
    __syncthreads();                    // Bs reads done before next gather
  }

  // ---- epilogue: out[(b*CC+co)*NPIX + pix] = relu(acc + bias) ----
#pragma unroll
  for (int i = 0; i < 4; ++i) {
    int pix = pix0 + wn + r16;
#pragma unroll
    for (int r = 0; r < 4; ++r) {
      int co = wm + i * 16 + q4 * 4 + r;
      float v = acc[i][r] + bias[co];
      out[(size_t)(b * CC + co) * NPIX + pix] = fmaxf(v, 0.f);
    }
  }
}

extern "C" void kernel_launch(void* const* d_in, const int* in_sizes, int n_in,
                              void* d_out, int out_size, void* d_ws, size_t ws_size,
                              hipStream_t stream) {
  const float* feat  = (const float*)d_in[0];
  const float* calib = (const float*)d_in[1];
  const float* grid  = (const float*)d_in[2];
  const float* Wc    = (const float*)d_in[3];
  const float* bc    = (const float*)d_in[4];
  float* out = (float*)d_out;

  char* ws = (char*)d_ws;
  const size_t SZ_INTEG = (size_t)BB * HH * WW * CC * 4;   // 62,914,560
  const size_t SZ_VOX   = (size_t)NDIM * KDIM * 2;         // 83,886,080 (unused slot kept)
  const size_t SZ_WBF   = (size_t)CC * KDIM * 2;           //    655,360
  const size_t SZ_CRD   = (size_t)BB * NLAY * NPIX * 16;   //  2,621,440
  const size_t SZ_SCL   = (size_t)BB * NLAY * NPIX * 4;    //    655,360
  const size_t SZ_MSK   = (size_t)NGRP * NLAY;             //      1,280
  if (ws_size < SZ_INTEG + SZ_VOX + SZ_WBF + SZ_CRD + SZ_SCL + SZ_MSK) return;

  float*   integ  = (float*)ws;
  __bf16*  Wbf    = (__bf16*)(ws + SZ_INTEG + SZ_VOX);
  float4*  coords = (float4*)(ws + SZ_INTEG + SZ_VOX + SZ_WBF);
  float*   scales = (float*)(ws + SZ_INTEG + SZ_VOX + SZ_WBF + SZ_CRD);
  uint8_t* mask8  = (uint8_t*)(ws + SZ_INTEG + SZ_VOX + SZ_WBF + SZ_CRD + SZ_SCL);

  k1f<<<dim3(BB * HH * 8 + 480), dim3(1024), 0, stream>>>(
      feat, integ, grid, calib, Wc, coords, scales, Wbf, mask8);
  k2_scan<<<dim3(BB * WW), dim3(256), 0, stream>>>(integ);
  k46<<<dim3(NDIM / 32), dim3(512), 0, stream>>>(Wbf, integ, coords, scales, bc, out, mask8);
}